// Round 10
// baseline (159.073 us; speedup 1.0000x reference)
//
#include <hip/hip_runtime.h>
#include <math.h>

typedef _Float16 half_t;
typedef _Float16 h2 __attribute__((ext_vector_type(2)));
typedef unsigned int uint;
typedef unsigned long long u64;

#define TPB 256

// pack two floats into a half2 bit pattern
__device__ __forceinline__ uint pack_h2f(float a, float b) {
  half_t ha = (half_t)a, hb = (half_t)b;
  unsigned short ua = __builtin_bit_cast(unsigned short, ha);
  unsigned short ub = __builtin_bit_cast(unsigned short, hb);
  return (uint)ua | ((uint)ub << 16);
}

__device__ __forceinline__ float silu_f(float x) {
  float e = __expf(-x);
  return x * __builtin_amdgcn_rcpf(1.0f + e);
}

// acc += silu*bw + sum_g basis[g]*w[g]   (fp16 dot2 pairs, fp32 accumulate)
// w = 5 uniform dwords in GLOBAL memory (scalar-cache path; K2/K3 evidence)
__device__ __forceinline__ float dot8(uint d0, uint d1, uint d2, uint d3,
                                      float sv, const uint* __restrict__ w,
                                      float acc) {
  acc = fmaf(sv, __uint_as_float(w[4]), acc);
#if __has_builtin(__builtin_amdgcn_fdot2)
  acc = __builtin_amdgcn_fdot2(__builtin_bit_cast(h2, d0), __builtin_bit_cast(h2, w[0]), acc, false);
  acc = __builtin_amdgcn_fdot2(__builtin_bit_cast(h2, d1), __builtin_bit_cast(h2, w[1]), acc, false);
  acc = __builtin_amdgcn_fdot2(__builtin_bit_cast(h2, d2), __builtin_bit_cast(h2, w[2]), acc, false);
  acc = __builtin_amdgcn_fdot2(__builtin_bit_cast(h2, d3), __builtin_bit_cast(h2, w[3]), acc, false);
#else
  uint dd[4] = {d0, d1, d2, d3};
#pragma unroll
  for (int k = 0; k < 4; ++k) {
    h2 f = __builtin_bit_cast(h2, dd[k]);
    h2 wv = __builtin_bit_cast(h2, w[k]);
    acc = fmaf((float)f.x, (float)wv.x, acc);
    acc = fmaf((float)f.y, (float)wv.y, acc);
  }
#endif
  return acc;
}

// Uniform-knot cubic B-spline dense-8 fp16 fragment via 128-bit shift scatter
// (numerics validated K4/K5/K7/K8/K9, absmax <= 0.0156).
__device__ __forceinline__ uint4 make_basis(float x) {
  float s = fmaf(x, 2.5f, 5.5f);       // (x - (-2.2)) / 0.4
  float sf = floorf(s);
  float t = s - sf;
  int p = (int)sf - 3;                 // first nonzero basis index (may be <0)
  float omt = 1.0f - t, t2 = t * t;
  float B0 = (1.0f / 6.0f) * omt * omt * omt;
  float B3 = (1.0f / 6.0f) * t2 * t;
  float B1 = fmaf(0.5f * t, t2, 2.0f / 3.0f - t2);
  float B2 = 1.0f - B0 - B1 - B3;      // partition of unity
  u64 A = ((u64)pack_h2f(B2, B3) << 32) | pack_h2f(B0, B1);
  int n = p < 0 ? -p : 0;              // halves below 0: pre-drop
  A = (n >= 4) ? 0ull : (A >> (16 * n));
  int pc = p < 0 ? 0 : (p > 9 ? 9 : p);
  int sh = 16 * pc;                    // 0..144
  u64 lo = (sh < 64) ? (A << sh) : 0ull;
  u64 hi = (sh == 0) ? 0ull
         : (sh < 64) ? (A >> (64 - sh))
         : (sh < 128) ? (A << (sh - 64)) : 0ull;
  return make_uint4((uint)lo, (uint)(lo >> 32), (uint)hi, (uint)(hi >> 32));
}

// Packed fp16 weights in d_ws (global; scalar-cache reads):
// W[t*5]        t=o*9+tap        (layer 1, 18 entries)
// W[90 + q*5]   q=(o*2+ci)*9+tap (layer 2, 36 entries)
__global__ void pack_w(const float* __restrict__ bw1, const float* __restrict__ sw1,
                       const float* __restrict__ sc1, const float* __restrict__ bw2,
                       const float* __restrict__ sw2, const float* __restrict__ sc2,
                       uint* __restrict__ W) {
  const int t = threadIdx.x;
  if (t < 18) {
    const float scv = sc1[t];
    uint* dst = W + t * 5;
#pragma unroll
    for (int j = 0; j < 4; ++j)
      dst[j] = pack_h2f(sw1[t * 8 + 2 * j] * scv, sw1[t * 8 + 2 * j + 1] * scv);
    dst[4] = __float_as_uint(bw1[t]);
  } else if (t < 54) {
    const int q = t - 18;
    const float scv = sc2[q];
    uint* dst = W + 90 + q * 5;
#pragma unroll
    for (int j = 0; j < 4; ++j)
      dst[j] = pack_h2f(sw2[q * 8 + 2 * j] * scv, sw2[q * 8 + 2 * j + 1] * scv);
    dst[4] = __float_as_uint(bw2[q]);
  }
}

// LDS dword map (19.6 KB -> 8 blocks/CU, 32 waves/CU):
//  F1D [0,3136):     784 x uint4 basis frags (28x28 INTERIOR only)
//  F2D [3136,4704):  392 x uint4 basis frags (2ch x 14x14)
//  F2S [4704,4900):  392 x fp16 silu (half-indexed)
//  P   alias [0,784): f32 partials for stage 4 (F1D dead by then)
#define F2DB 3136
#define F2SB 4704

__global__ __launch_bounds__(TPB, 8) void kan_fwd(
    const float* __restrict__ x, const uint* __restrict__ W,
    float* __restrict__ out)
{
  __shared__ __align__(16) uint lds[4900];
  half_t* F2S = (half_t*)&lds[F2SB];
  float* P = (float*)lds;

  const int tid = threadIdx.x;
  const float* xb = x + (size_t)blockIdx.x * 784;

  // basis(0) (padding): halves 2..5 = {1/48, 23/48, 23/48, 1/48}
  const uint F0d1 = pack_h2f(1.0f / 48.0f, 23.0f / 48.0f);
  const uint F0d2 = pack_h2f(23.0f / 48.0f, 1.0f / 48.0f);

  // ---- Stage 1: basis frags of the 28x28 interior, one b128 per pixel ----
  for (int s = tid; s < 784; s += TPB) {
    uint4 bs = make_basis(xb[s]);
    *(uint4*)&lds[s * 4] = bs;
  }
  __syncthreads();

  // ---- Stage 2: L1 conv (2x2 pool quad per thread) + pool + F2 features ----
  if (tid < 196) {
    const int ph = tid / 14, pw = tid % 14;
    float acc[2][4];
#pragma unroll
    for (int o = 0; o < 2; ++o)
#pragma unroll
      for (int q = 0; q < 4; ++q) acc[o][q] = 0.0f;
#pragma unroll
    for (int r = 0; r < 4; ++r) {
      const int ir = 2 * ph + r - 1;
#pragma unroll
      for (int c = 0; c < 4; ++c) {
        const int ic = 2 * pw + c - 1;
        const bool ok = ((uint)ir < 28u) && ((uint)ic < 28u);
        const int idx = min(max(ir * 28 + ic, 0), 783);
        // silu input from global (TA pipe, L1-hot); frag from LDS; OOB -> x=0
        const float xv = xb[idx];
        const float sv = ok ? silu_f(xv) : 0.0f;
        const uint4 d = *(const uint4*)&lds[idx * 4];
        const uint d0 = ok ? d.x : 0u;
        const uint d1 = ok ? d.y : F0d1;
        const uint d2 = ok ? d.z : F0d2;
        const uint d3 = ok ? d.w : 0u;
#pragma unroll
        for (int dh = 0; dh < 2; ++dh) {
          if (r - dh < 0 || r - dh > 2) continue;
#pragma unroll
          for (int dw = 0; dw < 2; ++dw) {
            if (c - dw < 0 || c - dw > 2) continue;
            const int tap = (r - dh) * 3 + (c - dw);
#pragma unroll
            for (int o = 0; o < 2; ++o)
              acc[o][dh * 2 + dw] =
                  dot8(d0, d1, d2, d3, sv, W + (o * 9 + tap) * 5, acc[o][dh * 2 + dw]);
          }
        }
      }
    }
#pragma unroll
    for (int o = 0; o < 2; ++o) {
      float m = fmaxf(fmaxf(acc[o][0], acc[o][1]), fmaxf(acc[o][2], acc[o][3]));
      const int fi = o * 196 + tid;
      uint4 bm = make_basis(m);
      *(uint4*)&lds[F2DB + fi * 4] = bm;
      F2S[fi] = (half_t)silu_f(m);     // fp16 silu plane (K9-validated)
    }
  }
  __syncthreads();

  // ---- Stage 3: L2 conv; one wave per (o,ci), lane = 7x7 pool pos ----
  {
    const int wid = __builtin_amdgcn_readfirstlane(tid >> 6);  // = o*2+ci
    const int lane = tid & 63;
    if (lane < 49) {
      const int ci = wid & 1;
      const int ph = lane / 7, pw = lane % 7;
      float pa[4] = {0.0f, 0.0f, 0.0f, 0.0f};
#pragma unroll
      for (int r = 0; r < 4; ++r) {
        const int row = 2 * ph + r - 1;
        const int rcl = min(max(row, 0), 13);
#pragma unroll
        for (int c = 0; c < 4; ++c) {
          const int col = 2 * pw + c - 1;
          const bool ok = ((uint)row < 14u) && ((uint)col < 14u);
          const int ccl = min(max(col, 0), 13);
          const int idx = ci * 196 + rcl * 14 + ccl;
          const uint4 d = *(const uint4*)&lds[F2DB + idx * 4];
          float sv = (float)F2S[idx];
          sv = ok ? sv : 0.0f;                  // silu(0) = 0
          const uint d0 = ok ? d.x : 0u;
          const uint d1 = ok ? d.y : F0d1;
          const uint d2 = ok ? d.z : F0d2;
          const uint d3 = ok ? d.w : 0u;
#pragma unroll
          for (int dh = 0; dh < 2; ++dh) {
            if (r - dh < 0 || r - dh > 2) continue;
#pragma unroll
            for (int dw = 0; dw < 2; ++dw) {
              if (c - dw < 0 || c - dw > 2) continue;
              const int tap = (r - dh) * 3 + (c - dw);
              pa[dh * 2 + dw] =
                  dot8(d0, d1, d2, d3, sv, W + 90 + (wid * 9 + tap) * 5, pa[dh * 2 + dw]);
            }
          }
        }
      }
      *(float4*)&P[(wid * 49 + lane) * 4] = make_float4(pa[0], pa[1], pa[2], pa[3]);
    }
  }
  __syncthreads();

  // ---- Stage 4: sum input channels, 2x2 maxpool, write (2,7,7) flat ----
  if (tid < 98) {
    const int o = tid / 49, pos = tid % 49;
    const float4 p0 = *(const float4*)&P[((o * 2 + 0) * 49 + pos) * 4];
    const float4 p1 = *(const float4*)&P[((o * 2 + 1) * 49 + pos) * 4];
    float m = fmaxf(fmaxf(p0.x + p1.x, p0.y + p1.y), fmaxf(p0.z + p1.z, p0.w + p1.w));
    out[(size_t)blockIdx.x * 98 + tid] = m;
  }
}

extern "C" void kernel_launch(void* const* d_in, const int* in_sizes, int n_in,
                              void* d_out, int out_size, void* d_ws, size_t ws_size,
                              hipStream_t stream) {
  const float* x   = (const float*)d_in[0];
  const float* bw1 = (const float*)d_in[1];
  const float* sw1 = (const float*)d_in[2];
  const float* sc1 = (const float*)d_in[3];
  const float* bw2 = (const float*)d_in[4];
  const float* sw2 = (const float*)d_in[5];
  const float* sc2 = (const float*)d_in[6];
  float* out = (float*)d_out;
  uint* W = (uint*)d_ws;  // 270 dwords
  const int B = in_sizes[0] / 784;  // 2048
  pack_w<<<1, 64, 0, stream>>>(bw1, sw1, sc1, bw2, sw2, sc2, W);
  kan_fwd<<<B, TPB, 0, stream>>>(x, W, out);
}

// Round 11
// 93.988 us; speedup vs baseline: 1.6925x; 1.6925x over previous
//
#include <hip/hip_runtime.h>
#include <math.h>

typedef _Float16 half_t;
typedef _Float16 h2 __attribute__((ext_vector_type(2)));
typedef unsigned int uint;
typedef unsigned long long u64;

#define TPB 256

// pack two floats into a half2 bit pattern
__device__ __forceinline__ uint pack_h2f(float a, float b) {
  half_t ha = (half_t)a, hb = (half_t)b;
  unsigned short ua = __builtin_bit_cast(unsigned short, ha);
  unsigned short ub = __builtin_bit_cast(unsigned short, hb);
  return (uint)ua | ((uint)ub << 16);
}

__device__ __forceinline__ float silu_f(float x) {
  float e = __expf(-x);
  return x * __builtin_amdgcn_rcpf(1.0f + e);
}

// acc += silu*bw + sum_g basis[g]*w[g]   (fp16 dot2 pairs, fp32 accumulate)
// w = 5 uniform dwords in GLOBAL memory (scalar-cache path; K2/K3 evidence)
__device__ __forceinline__ float dot8(uint d0, uint d1, uint d2, uint d3,
                                      float sv, const uint* __restrict__ w,
                                      float acc) {
  acc = fmaf(sv, __uint_as_float(w[4]), acc);
#if __has_builtin(__builtin_amdgcn_fdot2)
  acc = __builtin_amdgcn_fdot2(__builtin_bit_cast(h2, d0), __builtin_bit_cast(h2, w[0]), acc, false);
  acc = __builtin_amdgcn_fdot2(__builtin_bit_cast(h2, d1), __builtin_bit_cast(h2, w[1]), acc, false);
  acc = __builtin_amdgcn_fdot2(__builtin_bit_cast(h2, d2), __builtin_bit_cast(h2, w[2]), acc, false);
  acc = __builtin_amdgcn_fdot2(__builtin_bit_cast(h2, d3), __builtin_bit_cast(h2, w[3]), acc, false);
#else
  uint dd[4] = {d0, d1, d2, d3};
#pragma unroll
  for (int k = 0; k < 4; ++k) {
    h2 f = __builtin_bit_cast(h2, dd[k]);
    h2 wv = __builtin_bit_cast(h2, w[k]);
    acc = fmaf((float)f.x, (float)wv.x, acc);
    acc = fmaf((float)f.y, (float)wv.y, acc);
  }
#endif
  return acc;
}

// Uniform-knot cubic B-spline dense-8 fp16 fragment via 128-bit shift scatter
// (numerics validated K4/K5/K7-K10, absmax <= 0.0156).
// NOTE: make_basis(0) yields exactly the padding fragment (halves 2..5 =
// {1/48, 23/48, 23/48, 1/48}) and silu(0)=0 — so recompute-at-use needs NO
// border selects: just zero the OOB input.
__device__ __forceinline__ uint4 make_basis(float x) {
  float s = fmaf(x, 2.5f, 5.5f);       // (x - (-2.2)) / 0.4
  float sf = floorf(s);
  float t = s - sf;
  int p = (int)sf - 3;                 // first nonzero basis index (may be <0)
  float omt = 1.0f - t, t2 = t * t;
  float B0 = (1.0f / 6.0f) * omt * omt * omt;
  float B3 = (1.0f / 6.0f) * t2 * t;
  float B1 = fmaf(0.5f * t, t2, 2.0f / 3.0f - t2);
  float B2 = 1.0f - B0 - B1 - B3;      // partition of unity
  u64 A = ((u64)pack_h2f(B2, B3) << 32) | pack_h2f(B0, B1);
  int n = p < 0 ? -p : 0;              // halves below 0: pre-drop
  A = (n >= 4) ? 0ull : (A >> (16 * n));
  int pc = p < 0 ? 0 : (p > 9 ? 9 : p);
  int sh = 16 * pc;                    // 0..144
  u64 lo = (sh < 64) ? (A << sh) : 0ull;
  u64 hi = (sh == 0) ? 0ull
         : (sh < 64) ? (A >> (64 - sh))
         : (sh < 128) ? (A << (sh - 64)) : 0ull;
  return make_uint4((uint)lo, (uint)(lo >> 32), (uint)hi, (uint)(hi >> 32));
}

// Packed fp16 weights in d_ws (global; scalar-cache reads):
// W[t*5]        t=o*9+tap        (layer 1, 18 entries)
// W[90 + q*5]   q=(o*2+ci)*9+tap (layer 2, 36 entries)
__global__ void pack_w(const float* __restrict__ bw1, const float* __restrict__ sw1,
                       const float* __restrict__ sc1, const float* __restrict__ bw2,
                       const float* __restrict__ sw2, const float* __restrict__ sc2,
                       uint* __restrict__ W) {
  const int t = threadIdx.x;
  if (t < 18) {
    const float scv = sc1[t];
    uint* dst = W + t * 5;
#pragma unroll
    for (int j = 0; j < 4; ++j)
      dst[j] = pack_h2f(sw1[t * 8 + 2 * j] * scv, sw1[t * 8 + 2 * j + 1] * scv);
    dst[4] = __float_as_uint(bw1[t]);
  } else if (t < 54) {
    const int q = t - 18;
    const float scv = sc2[q];
    uint* dst = W + 90 + q * 5;
#pragma unroll
    for (int j = 0; j < 4; ++j)
      dst[j] = pack_h2f(sw2[q * 8 + 2 * j] * scv, sw2[q * 8 + 2 * j + 1] * scv);
    dst[4] = __float_as_uint(bw2[q]);
  }
}

// LDS dword map (10.2 KB — never the occupancy limiter):
//  F2D [0,1568):     392 x uint4 basis frags (2ch x 14x14)
//  F2S [1568,1764):  392 x fp16 silu (half-indexed)
//  P   [1764,2548):  784 f32 partials (separate: no aliasing hazards)
#define F2SB 1568
#define PB   1764

__global__ __launch_bounds__(TPB, 4) void kan_fwd(
    const float* __restrict__ x, const uint* __restrict__ W,
    float* __restrict__ out)
{
  __shared__ __align__(16) uint lds[2548];
  half_t* F2S = (half_t*)&lds[F2SB];
  float* P = (float*)&lds[PB];

  const int tid = threadIdx.x;
  const float* xb = x + (size_t)blockIdx.x * 784;

  // basis(0) (padding) fragment for stage B
  const uint F0d1 = pack_h2f(1.0f / 48.0f, 23.0f / 48.0f);
  const uint F0d2 = pack_h2f(23.0f / 48.0f, 1.0f / 48.0f);

  // ---- Stage A: L1 conv + pool + F2 features. No F1: basis recomputed in
  // registers at use (rolling row window, max 4 frags live). ----
  if (tid < 196) {
    const int ph = tid / 14, pw = tid % 14;
    // 16 inputs of the 4x4 window; OOB -> 0 (make_basis(0) == padding frag)
    float xv[16];
#pragma unroll
    for (int r = 0; r < 4; ++r) {
      const int ir = 2 * ph + r - 1;
#pragma unroll
      for (int c = 0; c < 4; ++c) {
        const int ic = 2 * pw + c - 1;
        const bool ok = ((uint)ir < 28u) && ((uint)ic < 28u);
        const int idx = ok ? (ir * 28 + ic) : 0;
        const float v = xb[idx];
        xv[r * 4 + c] = ok ? v : 0.0f;
      }
    }
    float acc[2][4];
#pragma unroll
    for (int o = 0; o < 2; ++o)
#pragma unroll
      for (int q = 0; q < 4; ++q) acc[o][q] = 0.0f;
#pragma unroll
    for (int r = 0; r < 4; ++r) {         // rolling by window row
      uint4 fr[4]; float sv[4];
#pragma unroll
      for (int c = 0; c < 4; ++c) {
        fr[c] = make_basis(xv[r * 4 + c]);
        sv[c] = silu_f(xv[r * 4 + c]);    // silu(0)=0 handles padding
      }
#pragma unroll
      for (int dh = 0; dh < 2; ++dh) {
        const int tr = r - dh;
        if (tr < 0 || tr > 2) continue;
#pragma unroll
        for (int tc = 0; tc < 3; ++tc) {
          const int tap = tr * 3 + tc;
#pragma unroll
          for (int dw = 0; dw < 2; ++dw) {
            const int c = tc + dw;
#pragma unroll
            for (int o = 0; o < 2; ++o)
              acc[o][dh * 2 + dw] =
                  dot8(fr[c].x, fr[c].y, fr[c].z, fr[c].w, sv[c],
                       W + (o * 9 + tap) * 5, acc[o][dh * 2 + dw]);
          }
        }
      }
    }
#pragma unroll
    for (int o = 0; o < 2; ++o) {
      const float m = fmaxf(fmaxf(acc[o][0], acc[o][1]), fmaxf(acc[o][2], acc[o][3]));
      const int fi = o * 196 + tid;
      uint4 bm = make_basis(m);
      *(uint4*)&lds[fi * 4] = bm;
      F2S[fi] = (half_t)silu_f(m);        // fp16 silu plane (K9/K10-validated)
    }
  }
  __syncthreads();

  // ---- Stage B: L2 conv; one wave per (o,ci), lane = 7x7 pool pos ----
  {
    const int wid = __builtin_amdgcn_readfirstlane(tid >> 6);  // = o*2+ci
    const int lane = tid & 63;
    if (lane < 49) {
      const int ci = wid & 1;
      const int ph = lane / 7, pw = lane % 7;
      float pa[4] = {0.0f, 0.0f, 0.0f, 0.0f};
#pragma unroll
      for (int r = 0; r < 4; ++r) {
        const int row = 2 * ph + r - 1;
        const int rcl = min(max(row, 0), 13);
#pragma unroll
        for (int c = 0; c < 4; ++c) {
          const int col = 2 * pw + c - 1;
          const bool ok = ((uint)row < 14u) && ((uint)col < 14u);
          const int ccl = min(max(col, 0), 13);
          const int idx = ci * 196 + rcl * 14 + ccl;
          const uint4 d = *(const uint4*)&lds[idx * 4];
          float sv = (float)F2S[idx];
          sv = ok ? sv : 0.0f;                  // silu(0) = 0
          const uint d0 = ok ? d.x : 0u;
          const uint d1 = ok ? d.y : F0d1;
          const uint d2 = ok ? d.z : F0d2;
          const uint d3 = ok ? d.w : 0u;
#pragma unroll
          for (int dh = 0; dh < 2; ++dh) {
            if (r - dh < 0 || r - dh > 2) continue;
#pragma unroll
            for (int dw = 0; dw < 2; ++dw) {
              if (c - dw < 0 || c - dw > 2) continue;
              const int tap = (r - dh) * 3 + (c - dw);
              pa[dh * 2 + dw] =
                  dot8(d0, d1, d2, d3, sv, W + 90 + (wid * 9 + tap) * 5, pa[dh * 2 + dw]);
            }
          }
        }
      }
      *(float4*)&P[(wid * 49 + lane) * 4] = make_float4(pa[0], pa[1], pa[2], pa[3]);
    }
  }
  __syncthreads();

  // ---- Stage C: sum input channels, 2x2 maxpool, write (2,7,7) flat ----
  if (tid < 98) {
    const int o = tid / 49, pos = tid % 49;
    const float4 p0 = *(const float4*)&P[((o * 2 + 0) * 49 + pos) * 4];
    const float4 p1 = *(const float4*)&P[((o * 2 + 1) * 49 + pos) * 4];
    float m = fmaxf(fmaxf(p0.x + p1.x, p0.y + p1.y), fmaxf(p0.z + p1.z, p0.w + p1.w));
    out[(size_t)blockIdx.x * 98 + tid] = m;
  }
}

extern "C" void kernel_launch(void* const* d_in, const int* in_sizes, int n_in,
                              void* d_out, int out_size, void* d_ws, size_t ws_size,
                              hipStream_t stream) {
  const float* x   = (const float*)d_in[0];
  const float* bw1 = (const float*)d_in[1];
  const float* sw1 = (const float*)d_in[2];
  const float* sc1 = (const float*)d_in[3];
  const float* bw2 = (const float*)d_in[4];
  const float* sw2 = (const float*)d_in[5];
  const float* sc2 = (const float*)d_in[6];
  float* out = (float*)d_out;
  uint* W = (uint*)d_ws;  // 270 dwords
  const int B = in_sizes[0] / 784;  // 2048
  pack_w<<<1, 64, 0, stream>>>(bw1, sw1, sc1, bw2, sw2, sc2, W);
  kan_fwd<<<B, TPB, 0, stream>>>(x, W, out);
}

// Round 12
// 89.847 us; speedup vs baseline: 1.7705x; 1.0461x over previous
//
#include <hip/hip_runtime.h>
#include <math.h>

typedef _Float16 half_t;
typedef _Float16 h2 __attribute__((ext_vector_type(2)));
typedef unsigned int uint;
typedef unsigned long long u64;

#define TPB 256
#define IPB 2    // images per block: halves barriers/image, doubles stage work

// pack two floats into a half2 bit pattern
__device__ __forceinline__ uint pack_h2f(float a, float b) {
  half_t ha = (half_t)a, hb = (half_t)b;
  unsigned short ua = __builtin_bit_cast(unsigned short, ha);
  unsigned short ub = __builtin_bit_cast(unsigned short, hb);
  return (uint)ua | ((uint)ub << 16);
}

__device__ __forceinline__ float silu_f(float x) {
  float e = __expf(-x);
  return x * __builtin_amdgcn_rcpf(1.0f + e);
}

// acc += silu*bw + sum_g basis[g]*w[g]   (fp16 dot2 pairs, fp32 accumulate)
// w = 5 uniform dwords in GLOBAL memory (scalar-cache path; K2/K3 evidence)
__device__ __forceinline__ float dot8(uint d0, uint d1, uint d2, uint d3,
                                      float sv, const uint* __restrict__ w,
                                      float acc) {
  acc = fmaf(sv, __uint_as_float(w[4]), acc);
#if __has_builtin(__builtin_amdgcn_fdot2)
  acc = __builtin_amdgcn_fdot2(__builtin_bit_cast(h2, d0), __builtin_bit_cast(h2, w[0]), acc, false);
  acc = __builtin_amdgcn_fdot2(__builtin_bit_cast(h2, d1), __builtin_bit_cast(h2, w[1]), acc, false);
  acc = __builtin_amdgcn_fdot2(__builtin_bit_cast(h2, d2), __builtin_bit_cast(h2, w[2]), acc, false);
  acc = __builtin_amdgcn_fdot2(__builtin_bit_cast(h2, d3), __builtin_bit_cast(h2, w[3]), acc, false);
#else
  uint dd[4] = {d0, d1, d2, d3};
#pragma unroll
  for (int k = 0; k < 4; ++k) {
    h2 f = __builtin_bit_cast(h2, dd[k]);
    h2 wv = __builtin_bit_cast(h2, w[k]);
    acc = fmaf((float)f.x, (float)wv.x, acc);
    acc = fmaf((float)f.y, (float)wv.y, acc);
  }
#endif
  return acc;
}

// Uniform-knot cubic B-spline dense-8 fp16 fragment via 128-bit shift scatter
// (numerics validated K4-K11, absmax <= 0.0156).
__device__ __forceinline__ uint4 make_basis(float x) {
  float s = fmaf(x, 2.5f, 5.5f);       // (x - (-2.2)) / 0.4
  float sf = floorf(s);
  float t = s - sf;
  int p = (int)sf - 3;                 // first nonzero basis index (may be <0)
  float omt = 1.0f - t, t2 = t * t;
  float B0 = (1.0f / 6.0f) * omt * omt * omt;
  float B3 = (1.0f / 6.0f) * t2 * t;
  float B1 = fmaf(0.5f * t, t2, 2.0f / 3.0f - t2);
  float B2 = 1.0f - B0 - B1 - B3;      // partition of unity
  u64 A = ((u64)pack_h2f(B2, B3) << 32) | pack_h2f(B0, B1);
  int n = p < 0 ? -p : 0;              // halves below 0: pre-drop
  A = (n >= 4) ? 0ull : (A >> (16 * n));
  int pc = p < 0 ? 0 : (p > 9 ? 9 : p);
  int sh = 16 * pc;                    // 0..144
  u64 lo = (sh < 64) ? (A << sh) : 0ull;
  u64 hi = (sh == 0) ? 0ull
         : (sh < 64) ? (A >> (64 - sh))
         : (sh < 128) ? (A << (sh - 64)) : 0ull;
  return make_uint4((uint)lo, (uint)(lo >> 32), (uint)hi, (uint)(hi >> 32));
}

// Packed fp16 weights in d_ws (global; scalar-cache reads):
// W[t*5]        t=o*9+tap        (layer 1, 18 entries)
// W[90 + q*5]   q=(o*2+ci)*9+tap (layer 2, 36 entries)
__global__ void pack_w(const float* __restrict__ bw1, const float* __restrict__ sw1,
                       const float* __restrict__ sc1, const float* __restrict__ bw2,
                       const float* __restrict__ sw2, const float* __restrict__ sc2,
                       uint* __restrict__ W) {
  const int t = threadIdx.x;
  if (t < 18) {
    const float scv = sc1[t];
    uint* dst = W + t * 5;
#pragma unroll
    for (int j = 0; j < 4; ++j)
      dst[j] = pack_h2f(sw1[t * 8 + 2 * j] * scv, sw1[t * 8 + 2 * j + 1] * scv);
    dst[4] = __float_as_uint(bw1[t]);
  } else if (t < 54) {
    const int q = t - 18;
    const float scv = sc2[q];
    uint* dst = W + 90 + q * 5;
#pragma unroll
    for (int j = 0; j < 4; ++j)
      dst[j] = pack_h2f(sw2[q * 8 + 2 * j] * scv, sw2[q * 8 + 2 * j + 1] * scv);
    dst[4] = __float_as_uint(bw2[q]);
  }
}

// LDS dword map, 2 images (39.2 KB -> 4 blocks/CU = 8 images/CU):
//  F1D [0,6272):      2 x 784 x uint4 basis frags (28x28 interior), s = img*784+px
//  F2D [6272,9408):   2 x 392 x uint4; 6272 + (img*392 + fi)*4
//  F2S [9408,9800):   2 x 392 fp16 silu; half-index img*392 + fi
//  P   alias [0,1568): f32 partials (img,wid,lane) — F1D dead in stages 3/4
#define F2DB 6272
#define F2SB 9408

__global__ __launch_bounds__(TPB, 4) void kan_fwd(
    const float* __restrict__ x, const uint* __restrict__ W,
    float* __restrict__ out)
{
  __shared__ __align__(16) uint lds[9800];
  half_t* F2S = (half_t*)&lds[F2SB];
  float* P = (float*)lds;

  const int tid = threadIdx.x;
  const float* xB = x + (size_t)blockIdx.x * (784 * IPB);

  // basis(0) (padding): halves 2..5 = {1/48, 23/48, 23/48, 1/48}
  const uint F0d1 = pack_h2f(1.0f / 48.0f, 23.0f / 48.0f);
  const uint F0d2 = pack_h2f(23.0f / 48.0f, 1.0f / 48.0f);

  // ---- Stage 1: basis frags of both images' 28x28 interiors ----
  for (int s = tid; s < 784 * IPB; s += TPB) {
    uint4 bs = make_basis(xB[s]);         // s = img*784 + px, F1D laid out same
    *(uint4*)&lds[s * 4] = bs;
  }
  __syncthreads();

  // ---- Stage 2: L1 conv (2x2 pool quad per task) + pool + F2 features ----
  for (int task = tid; task < 196 * IPB; task += TPB) {
    const int img = task / 196, q = task - img * 196;
    const int ph = q / 14, pw = q - (q / 14) * 14;
    const float* xb = xB + img * 784;
    const uint* F1 = &lds[img * 784 * 4];
    float acc[2][4];
#pragma unroll
    for (int o = 0; o < 2; ++o)
#pragma unroll
      for (int j = 0; j < 4; ++j) acc[o][j] = 0.0f;
#pragma unroll
    for (int r = 0; r < 4; ++r) {
      const int ir = 2 * ph + r - 1;
#pragma unroll
      for (int c = 0; c < 4; ++c) {
        const int ic = 2 * pw + c - 1;
        const bool ok = ((uint)ir < 28u) && ((uint)ic < 28u);
        const int idx = min(max(ir * 28 + ic, 0), 783);
        const float xv = xb[idx];               // TA pipe, L1-hot
        const float sv = ok ? silu_f(xv) : 0.0f;
        const uint4 d = *(const uint4*)&F1[idx * 4];
        const uint d0 = ok ? d.x : 0u;
        const uint d1 = ok ? d.y : F0d1;
        const uint d2 = ok ? d.z : F0d2;
        const uint d3 = ok ? d.w : 0u;
#pragma unroll
        for (int dh = 0; dh < 2; ++dh) {
          if (r - dh < 0 || r - dh > 2) continue;
#pragma unroll
          for (int dw = 0; dw < 2; ++dw) {
            if (c - dw < 0 || c - dw > 2) continue;
            const int tap = (r - dh) * 3 + (c - dw);
#pragma unroll
            for (int o = 0; o < 2; ++o)
              acc[o][dh * 2 + dw] =
                  dot8(d0, d1, d2, d3, sv, W + (o * 9 + tap) * 5, acc[o][dh * 2 + dw]);
          }
        }
      }
    }
#pragma unroll
    for (int o = 0; o < 2; ++o) {
      float m = fmaxf(fmaxf(acc[o][0], acc[o][1]), fmaxf(acc[o][2], acc[o][3]));
      const int fi = img * 392 + o * 196 + q;
      uint4 bm = make_basis(m);
      *(uint4*)&lds[F2DB + fi * 4] = bm;
      F2S[fi] = (half_t)silu_f(m);
    }
  }
  __syncthreads();

  // ---- Stage 3: L2 conv; 8 (img,wid) wave-tasks over 4 waves, 2 rounds ----
  {
    const int wv = __builtin_amdgcn_readfirstlane(tid >> 6);
    const int lane = tid & 63;
    if (lane < 49) {
      const int ph = lane / 7, pw = lane % 7;
#pragma unroll
      for (int img = 0; img < IPB; ++img) {
        const int wid = wv;                 // = o*2+ci
        const int ci = wid & 1;
        float pa[4] = {0.0f, 0.0f, 0.0f, 0.0f};
#pragma unroll
        for (int r = 0; r < 4; ++r) {
          const int row = 2 * ph + r - 1;
          const int rcl = min(max(row, 0), 13);
#pragma unroll
          for (int c = 0; c < 4; ++c) {
            const int col = 2 * pw + c - 1;
            const bool ok = ((uint)row < 14u) && ((uint)col < 14u);
            const int ccl = min(max(col, 0), 13);
            const int idx = img * 392 + ci * 196 + rcl * 14 + ccl;
            const uint4 d = *(const uint4*)&lds[F2DB + idx * 4];
            float sv = (float)F2S[idx];
            sv = ok ? sv : 0.0f;
            const uint d0 = ok ? d.x : 0u;
            const uint d1 = ok ? d.y : F0d1;
            const uint d2 = ok ? d.z : F0d2;
            const uint d3 = ok ? d.w : 0u;
#pragma unroll
            for (int dh = 0; dh < 2; ++dh) {
              if (r - dh < 0 || r - dh > 2) continue;
#pragma unroll
              for (int dw = 0; dw < 2; ++dw) {
                if (c - dw < 0 || c - dw > 2) continue;
                const int tap = (r - dh) * 3 + (c - dw);
                pa[dh * 2 + dw] =
                    dot8(d0, d1, d2, d3, sv, W + 90 + (wid * 9 + tap) * 5, pa[dh * 2 + dw]);
              }
            }
          }
        }
        *(float4*)&P[((img * 4 + wid) * 49 + lane) * 4] =
            make_float4(pa[0], pa[1], pa[2], pa[3]);
      }
    }
  }
  __syncthreads();

  // ---- Stage 4: sum input channels, 2x2 maxpool, write (2,7,7) flat ----
  if (tid < 98 * IPB) {
    const int img = tid / 98, t = tid - img * 98;
    const int o = t / 49, pos = t % 49;
    const float4 p0 = *(const float4*)&P[((img * 4 + o * 2 + 0) * 49 + pos) * 4];
    const float4 p1 = *(const float4*)&P[((img * 4 + o * 2 + 1) * 49 + pos) * 4];
    float m = fmaxf(fmaxf(p0.x + p1.x, p0.y + p1.y), fmaxf(p0.z + p1.z, p0.w + p1.w));
    out[((size_t)blockIdx.x * IPB + img) * 98 + t] = m;
  }
}

extern "C" void kernel_launch(void* const* d_in, const int* in_sizes, int n_in,
                              void* d_out, int out_size, void* d_ws, size_t ws_size,
                              hipStream_t stream) {
  const float* x   = (const float*)d_in[0];
  const float* bw1 = (const float*)d_in[1];
  const float* sw1 = (const float*)d_in[2];
  const float* sc1 = (const float*)d_in[3];
  const float* bw2 = (const float*)d_in[4];
  const float* sw2 = (const float*)d_in[5];
  const float* sc2 = (const float*)d_in[6];
  float* out = (float*)d_out;
  uint* W = (uint*)d_ws;  // 270 dwords
  const int B = in_sizes[0] / 784;  // 2048 (even)
  pack_w<<<1, 64, 0, stream>>>(bw1, sw1, sc1, bw2, sw2, sc2, W);
  kan_fwd<<<B / IPB, TPB, 0, stream>>>(x, W, out);
}